// Round 7
// baseline (661.744 us; speedup 1.0000x reference)
//
#include <hip/hip_runtime.h>
#include <stdint.h>

#define NB 8
#define NN 1024
#define LOG2E 1.44269504088896f

typedef short short8 __attribute__((ext_vector_type(8)));
typedef float floatx4 __attribute__((ext_vector_type(4)));

static __device__ __forceinline__ short f2bf(float x) {   // round-nearest-even
    union { float f; uint32_t u; } v; v.f = x;
    uint32_t r = (v.u + 0x7fffu + ((v.u >> 16) & 1u)) >> 16;
    return (short)r;
}

// ---------------- shared-memory union across phases ----------------
struct SmemGemm { ushort t[2][64][88]; };                    // 22528 B
struct SmemAgg  { float s[NN]; float red4[4]; ushort buf[4][4096]; }; // 36880 B
struct SmemRead { ushort xs[64][88]; ushort wns[64][88]; float gcs; };
union SmemU { SmemGemm g; SmemAgg a; SmemRead r; };

struct GArgs {
    const int* adj;
    const float *x0, *w1, *w2, *w3, *wn;
    const float *as1, *ad1, *b1, *as2, *ad2, *b2, *as3, *ad3, *b3;
    const float *bn, *wg, *bg, *wv, *bv;
    uint64_t* amask;
    ushort *hbT, *xbA, *xbB, *x0b, *wb1, *wb2, *wb3, *wnb;
    float *s_buf, *d_buf, *gsum;
    unsigned* bar;
    float* outp;
    int nblk;
};

// ---------------- grid barrier: monotonic counter, bounded spin ----------------
static __device__ __forceinline__ void gridbar(unsigned* cnt, unsigned target) {
    __threadfence();                      // all threads: drain + device-visible stores
    __syncthreads();
    if (threadIdx.x == 0) {
        __hip_atomic_fetch_add(cnt, 1u, __ATOMIC_RELEASE, __HIP_MEMORY_SCOPE_AGENT);
        unsigned guard = 0;
        while (__hip_atomic_load(cnt, __ATOMIC_ACQUIRE, __HIP_MEMORY_SCOPE_AGENT) < target) {
            __builtin_amdgcn_s_sleep(2);
            if (++guard > (1u << 20)) break;   // fail loudly (wrong result), never hang
        }
    }
    __syncthreads();
    __threadfence();                      // acquire side: invalidate for fresh reads
}

// ---------------- phase: MFMA GEMM tile (64x64), fused s/d epilogue ----------
template<int K>
static __device__ void gemm_tile(SmemU& S, const ushort* __restrict__ X,
        const ushort* __restrict__ Wt, ushort* __restrict__ hbT,
        const float* __restrict__ asrc, const float* __restrict__ adst,
        float* __restrict__ s_t, float* __restrict__ d_t, int nheads,
        int mt, int hd) {
    int m0 = mt * 64, n0 = hd * 64;
    int tid = threadIdx.x, w = tid >> 6, L = tid & 63;
    int m15 = L & 15, kq = L >> 4;
    __syncthreads();                      // smem reuse guard
    floatx4 acc[4];
#pragma unroll
    for (int ct = 0; ct < 4; ++ct) acc[ct] = (floatx4){0.f, 0.f, 0.f, 0.f};

    for (int k0 = 0; k0 < K; k0 += 64) {
#pragma unroll
        for (int it = 0; it < 2; ++it) {
            int idx = tid + it * 256;
            int r = idx >> 3, sg = idx & 7;
            *(uint4*)&S.g.t[0][r][sg * 8] = *(const uint4*)&X[(size_t)(m0 + r) * K + k0 + sg * 8];
            *(uint4*)&S.g.t[1][r][sg * 8] = *(const uint4*)&Wt[(size_t)(n0 + r) * K + k0 + sg * 8];
        }
        __syncthreads();
#pragma unroll
        for (int ks = 0; ks < 2; ++ks) {
            short8 a = *(const short8*)&S.g.t[0][16 * w + m15][ks * 32 + kq * 8];
#pragma unroll
            for (int ct = 0; ct < 4; ++ct) {
                short8 bfr = *(const short8*)&S.g.t[1][ct * 16 + m15][ks * 32 + kq * 8];
                acc[ct] = __builtin_amdgcn_mfma_f32_16x16x32_bf16(a, bfr, acc[ct], 0, 0, 0);
            }
        }
        __syncthreads();
    }

    float asv[4], adv[4];
#pragma unroll
    for (int ct = 0; ct < 4; ++ct) {
        asv[ct] = asrc[hd * 64 + ct * 16 + m15];
        adv[ct] = adst[hd * 64 + ct * 16 + m15];
    }
#pragma unroll
    for (int r = 0; r < 4; ++r) {
        float sp = acc[0][r] * asv[0] + acc[1][r] * asv[1] + acc[2][r] * asv[2] + acc[3][r] * asv[3];
        float dp = acc[0][r] * adv[0] + acc[1][r] * adv[1] + acc[2][r] * adv[2] + acc[3][r] * adv[3];
#pragma unroll
        for (int off = 1; off < 16; off <<= 1) {
            sp += __shfl_xor(sp, off);
            dp += __shfl_xor(dp, off);
        }
        if (m15 == 0) {
            int mg = m0 + 16 * w + kq * 4 + r;
            int bb = mg >> 10, node = mg & 1023;
            s_t[((size_t)(bb * nheads + hd)) * NN + node] = sp;
            d_t[((size_t)(bb * nheads + hd)) * NN + node] = dp;
        }
    }

    ushort* tb = (ushort*)&S.g.t[0][0][0];   // stride-80 transpose staging
#pragma unroll
    for (int ct = 0; ct < 4; ++ct)
#pragma unroll
        for (int r = 0; r < 4; ++r)
            tb[(ct * 16 + m15) * 80 + 16 * w + kq * 4 + r] = (ushort)f2bf(acc[ct][r]);
    __syncthreads();
    int bb = m0 >> 10, node0 = m0 & 1023;
    size_t base = ((size_t)(bb * nheads + hd) * 64) * NN + node0;
    int c = tid >> 2, s2 = (tid & 3) * 2;
#pragma unroll
    for (int e = 0; e < 2; ++e) {
        int sg = s2 + e;
        *(uint4*)&hbT[base + (size_t)c * NN + sg * 8] = *(const uint4*)&tb[c * 80 + sg * 8];
    }
}

// ---------------- phase: wave-autonomous masked-softmax aggregation ----------
static __device__ void agg_tile(SmemU& S, const ushort* __restrict__ hbT,
        const uint64_t* __restrict__ am, const float* __restrict__ s_t,
        const float* __restrict__ d_t, const float* __restrict__ bias,
        ushort* __restrict__ Xb, float* __restrict__ gsum, int nheads,
        int do_colsum, int it, int hd, int b) {
    float* s_lds = S.a.s;
    int i0 = it * 16;
    int HC = nheads * 64;
    int tid = threadIdx.x, w = tid >> 6, L = tid & 63;
    int m15 = L & 15, kq = L >> 4;
    __syncthreads();                      // smem reuse guard

    const float* srow = s_t + ((size_t)b * nheads + hd) * NN;
    float4 s4 = ((const float4*)srow)[tid];
    *(float4*)&s_lds[tid * 4] = s4;
    float lm = fmaxf(fmaxf(s4.x, s4.y), fmaxf(s4.z, s4.w));
#pragma unroll
    for (int off = 32; off; off >>= 1) lm = fmaxf(lm, __shfl_xor(lm, off));
    if (L == 0) S.a.red4[w] = lm;

    const uint64_t* amrow = am + ((size_t)b * NN + i0 + m15) * 16 + w * 4;
    uint64_t aw[4];
    *(uint4*)&aw[0] = *(const uint4*)&amrow[0];
    *(uint4*)&aw[2] = *(const uint4*)&amrow[2];
    float d_i = d_t[((size_t)b * nheads + hd) * NN + i0 + m15];
    __syncthreads();

    float smax = fmaxf(fmaxf(S.a.red4[0], S.a.red4[1]), fmaxf(S.a.red4[2], S.a.red4[3]));
    float t0 = smax + d_i;
    float m_up = fmaxf(t0, 0.2f * t0);    // exp-safe upper bound (leaky monotone)
    float m2n = -m_up * LOG2E;

    floatx4 acc[4];
#pragma unroll
    for (int ct = 0; ct < 4; ++ct) acc[ct] = (floatx4){0.f, 0.f, 0.f, 0.f};
    float lsum = 0.f;

    const ushort* hbase = hbT + ((size_t)(b * nheads + hd) * 64) * NN;
    int r8 = L >> 3, sl = L & 7;
    int wofs = r8 * 64 + ((sl ^ r8) * 8);
    ushort* mybuf = S.a.buf[w];
    const ushort* gsrc = hbase + (size_t)r8 * NN + (w * 4) * 64 + sl * 8;

    uint4 pre[8];
#pragma unroll
    for (int e = 0; e < 8; ++e) pre[e] = *(const uint4*)(gsrc + (size_t)e * 8 * NN);

#pragma unroll
    for (int t = 0; t < 4; ++t) {
        int jc = w * 4 + t;
#pragma unroll
        for (int e = 0; e < 8; ++e) *(uint4*)&mybuf[wofs + e * 512] = pre[e];
        if (t < 3) {
#pragma unroll
            for (int e = 0; e < 8; ++e)
                pre[e] = *(const uint4*)(gsrc + (size_t)e * 8 * NN + (t + 1) * 64);
        }
        uint64_t word = aw[t];
#pragma unroll
        for (int ks = 0; ks < 2; ++ks) {
            int jb = jc * 64 + ks * 32 + kq * 8;
            float sv[8];
            *(float4*)&sv[0] = *(const float4*)&s_lds[jb];
            *(float4*)&sv[4] = *(const float4*)&s_lds[jb + 4];
            unsigned byte = (unsigned)((word >> (ks * 32 + kq * 8)) & 0xffull);
            unsigned ue[8];
#pragma unroll
            for (int u = 0; u < 8; ++u) {
                float sc = sv[u] + d_i;
                float lk = fmaxf(sc, 0.2f * sc);
#if __has_builtin(__builtin_amdgcn_exp2f)
                float arg = __builtin_fmaf(lk, LOG2E, m2n);
                arg = ((byte >> u) & 1u) ? arg : -1e30f;
                float e = __builtin_amdgcn_exp2f(arg);
#else
                float e = __expf(fminf(lk + m2n, 0.f));
                e = ((byte >> u) & 1u) ? e : 0.f;
#endif
                lsum += e;
                ue[u] = __float_as_uint(e);
            }
            unsigned pk[4];
#pragma unroll
            for (int k2 = 0; k2 < 4; ++k2)
#if __has_builtin(__builtin_amdgcn_perm)
                pk[k2] = __builtin_amdgcn_perm(ue[2 * k2 + 1], ue[2 * k2], 0x07060302u);
#else
                pk[k2] = (ue[2 * k2] >> 16) | (ue[2 * k2 + 1] & 0xffff0000u);
#endif
            short8 afrag;
            *(uint4*)&afrag = *(uint4*)&pk[0];
            int pslot = (ks * 4 + kq) ^ (m15 & 7);
#pragma unroll
            for (int ct = 0; ct < 4; ++ct) {
                short8 bfr = *(const short8*)&mybuf[(ct * 16 + m15) * 64 + pslot * 8];
                acc[ct] = __builtin_amdgcn_mfma_f32_16x16x32_bf16(afrag, bfr, acc[ct], 0, 0, 0);
            }
        }
    }

    lsum += __shfl_xor(lsum, 16);
    lsum += __shfl_xor(lsum, 32);

    float* fb = (float*)&S.a.buf[w][0];   // f32 overlay [16][68] + denom row
#pragma unroll
    for (int ct = 0; ct < 4; ++ct)
#pragma unroll
        for (int r = 0; r < 4; ++r)
            fb[(kq * 4 + r) * 68 + ct * 16 + m15] = acc[ct][r];
    if (kq == 0) fb[16 * 68 + m15] = lsum;
    __syncthreads();

    int rr = tid >> 4, c0 = (tid & 15) * 4;
    float s0 = 0.f, s1 = 0.f, s2 = 0.f, s3 = 0.f, ltot = 0.f;
#pragma unroll
    for (int w2 = 0; w2 < 4; ++w2) {
        const float* f2 = (const float*)&S.a.buf[w2][0];
        float4 a4 = *(const float4*)&f2[rr * 68 + c0];
        s0 += a4.x; s1 += a4.y; s2 += a4.z; s3 += a4.w;
        ltot += f2[16 * 68 + rr];
    }
    float li = 1.f / ltot;
    float4 bv = *(const float4*)&bias[hd * 64 + c0];
    float v0 = fmaxf(s0 * li + bv.x, 0.f);
    float v1 = fmaxf(s1 * li + bv.y, 0.f);
    float v2 = fmaxf(s2 * li + bv.z, 0.f);
    float v3 = fmaxf(s3 * li + bv.w, 0.f);
    ushort4 o;
    o.x = (ushort)f2bf(v0); o.y = (ushort)f2bf(v1);
    o.z = (ushort)f2bf(v2); o.w = (ushort)f2bf(v3);
    *(ushort4*)&Xb[((size_t)(b * NN + i0 + rr)) * HC + hd * 64 + c0] = o;

    if (do_colsum) {
        __syncthreads();
        float* cb = (float*)&S.a.buf[0][0];
        *(float4*)&cb[rr * 68 + c0] = make_float4(v0, v1, v2, v3);
        __syncthreads();
        if (tid < 64) {
            float s = 0.f;
#pragma unroll
            for (int r2 = 0; r2 < 16; ++r2) s += cb[r2 * 68 + tid];
            atomicAdd(&gsum[b * 64 + tid], s);
        }
    }
}

// ---------------- phase: fused readout ----------------
static __device__ void readout_tile(SmemU& S, const ushort* __restrict__ xb,
        const ushort* __restrict__ wnb, const float* __restrict__ bn,
        const float* __restrict__ wg, const float* __restrict__ bg,
        const float* __restrict__ wv, const float* __restrict__ bv,
        const float* __restrict__ gsum, float* __restrict__ outp, int bx, int b) {
    int n0 = bx * 64;
    int tid = threadIdx.x, w = tid >> 6, L = tid & 63;
    int m15 = L & 15, kq = L >> 4;
    __syncthreads();
#pragma unroll
    for (int it = 0; it < 2; ++it) {
        int idx = tid + it * 256;
        int r = idx >> 3, sg = idx & 7;
        *(uint4*)&S.r.xs[r][sg * 8]  = *(const uint4*)&xb[(size_t)(b * NN + n0 + r) * 64 + sg * 8];
        *(uint4*)&S.r.wns[r][sg * 8] = *(const uint4*)&wnb[r * 64 + sg * 8];
    }
    if (tid < 64) {
        float acc = bg[tid];
#pragma unroll 8
        for (int c = 0; c < 64; ++c) acc += gsum[b * 64 + c] * wg[tid * 64 + c];
        acc = fmaxf(acc, 0.f) * wv[64 + tid];
#pragma unroll
        for (int off = 32; off; off >>= 1) acc += __shfl_down(acc, off);
        if (tid == 0) S.r.gcs = acc + bv[0];
    }
    __syncthreads();

    floatx4 acc[4];
#pragma unroll
    for (int ct = 0; ct < 4; ++ct) acc[ct] = (floatx4){0.f, 0.f, 0.f, 0.f};
#pragma unroll
    for (int ks = 0; ks < 2; ++ks) {
        short8 a = *(const short8*)&S.r.xs[16 * w + m15][ks * 32 + kq * 8];
#pragma unroll
        for (int ct = 0; ct < 4; ++ct) {
            short8 bfr = *(const short8*)&S.r.wns[ct * 16 + m15][ks * 32 + kq * 8];
            acc[ct] = __builtin_amdgcn_mfma_f32_16x16x32_bf16(a, bfr, acc[ct], 0, 0, 0);
        }
    }
    float bnv[4], wvv[4];
#pragma unroll
    for (int ct = 0; ct < 4; ++ct) {
        bnv[ct] = bn[ct * 16 + m15];
        wvv[ct] = wv[ct * 16 + m15];
    }
    float gc = S.r.gcs;
#pragma unroll
    for (int r = 0; r < 4; ++r) {
        float rp = 0.f;
#pragma unroll
        for (int ct = 0; ct < 4; ++ct)
            rp += fmaxf(acc[ct][r] + bnv[ct], 0.f) * wvv[ct];
#pragma unroll
        for (int off = 1; off < 16; off <<= 1) rp += __shfl_xor(rp, off);
        if (m15 == 0)
            outp[(size_t)b * NN + n0 + 16 * w + kq * 4 + r] = rp + gc;
    }
}

// ---------------- the mega-kernel: all 8 phases, 7 grid barriers ----------------
__global__ __launch_bounds__(256) void gat_fused(GArgs A) {
    __shared__ SmemU S;
    int bid = blockIdx.x, tid = threadIdx.x;
    int nblk = A.nblk;
    int w = tid >> 6, L = tid & 63;
    unsigned bno = 0;

    // ---- P0: adjacency bitmask + bf16 conversions + gsum zero ----
    {
        int gw = bid * 4 + w, nw = nblk * 4;
        for (int row = gw; row < NB * NN; row += nw) {
            int b = row >> 10, i = row & 1023;
            const int* rp = A.adj + ((size_t)b * NN + i) * NN;
            uint64_t* op = A.amask + ((size_t)b * NN + i) * 16;
            for (int it = 0; it < 16; ++it) {
                int j = it * 64 + L;
                int v = (rp[j] > 0) || (j == i);
                uint64_t m = __ballot(v);
                if (L == 0) op[it] = m;
            }
        }
        for (int idx = bid * 256 + tid; idx < 156800; idx += nblk * 256) {
            if (idx < 156672) {
                const float* src; ushort* dst; int li;
                if (idx < 131072)      { src = A.x0; dst = A.x0b; li = idx; }
                else if (idx < 135168) { src = A.w1; dst = A.wb1; li = idx - 131072; }
                else if (idx < 151552) { src = A.w2; dst = A.wb2; li = idx - 135168; }
                else if (idx < 155648) { src = A.w3; dst = A.wb3; li = idx - 151552; }
                else                   { src = A.wn; dst = A.wnb; li = idx - 155648; }
                float4 v = ((const float4*)src)[li];
                ushort4 o;
                o.x = (ushort)f2bf(v.x); o.y = (ushort)f2bf(v.y);
                o.z = (ushort)f2bf(v.z); o.w = (ushort)f2bf(v.w);
                ((ushort4*)dst)[li] = o;
            } else {
                ((float4*)A.gsum)[idx - 156672] = make_float4(0.f, 0.f, 0.f, 0.f);
            }
        }
    }
    gridbar(A.bar, ++bno * (unsigned)nblk);

    // ---- P1: gemm layer 1 (K=64, H=4): 512 tiles ----
    for (int v = bid; v < 512; v += nblk)
        gemm_tile<64>(S, A.x0b, A.wb1, A.hbT, A.as1, A.ad1, A.s_buf, A.d_buf, 4, v & 127, v >> 7);
    gridbar(A.bar, ++bno * (unsigned)nblk);

    // ---- P2: agg layer 1: 2048 units ----
    for (int v = bid; v < 2048; v += nblk)
        agg_tile(S, A.hbT, A.amask, A.s_buf, A.d_buf, A.b1, A.xbA, A.gsum, 4, 0,
                 v & 63, (v >> 6) & 3, v >> 8);
    gridbar(A.bar, ++bno * (unsigned)nblk);

    // ---- P3: gemm layer 2 (K=256, H=4) ----
    for (int v = bid; v < 512; v += nblk)
        gemm_tile<256>(S, A.xbA, A.wb2, A.hbT, A.as2, A.ad2, A.s_buf, A.d_buf, 4, v & 127, v >> 7);
    gridbar(A.bar, ++bno * (unsigned)nblk);

    // ---- P4: agg layer 2 ----
    for (int v = bid; v < 2048; v += nblk)
        agg_tile(S, A.hbT, A.amask, A.s_buf, A.d_buf, A.b2, A.xbB, A.gsum, 4, 0,
                 v & 63, (v >> 6) & 3, v >> 8);
    gridbar(A.bar, ++bno * (unsigned)nblk);

    // ---- P5: gemm layer 3 (K=256, H=1): 128 tiles ----
    for (int v = bid; v < 128; v += nblk)
        gemm_tile<256>(S, A.xbB, A.wb3, A.hbT, A.as3, A.ad3, A.s_buf, A.d_buf, 1, v, 0);
    gridbar(A.bar, ++bno * (unsigned)nblk);

    // ---- P6: agg layer 3 + colsum: 512 units ----
    for (int v = bid; v < 512; v += nblk)
        agg_tile(S, A.hbT, A.amask, A.s_buf, A.d_buf, A.b3, A.xbA, A.gsum, 1, 1,
                 v & 63, 0, v >> 6);
    gridbar(A.bar, ++bno * (unsigned)nblk);

    // ---- P7: readout: 128 units ----
    for (int v = bid; v < 128; v += nblk)
        readout_tile(S, A.xbA, A.wnb, A.bn, A.wg, A.bg, A.wv, A.bv, A.gsum, A.outp,
                     v & 15, v >> 4);
}

extern "C" void kernel_launch(void* const* d_in, const int* in_sizes, int n_in,
                              void* d_out, int out_size, void* d_ws, size_t ws_size,
                              hipStream_t stream) {
    GArgs A;
    A.x0  = (const float*)d_in[0];
    A.adj = (const int*)  d_in[1];
    A.w1  = (const float*)d_in[2];
    A.as1 = (const float*)d_in[3];
    A.ad1 = (const float*)d_in[4];
    A.b1  = (const float*)d_in[5];
    A.w2  = (const float*)d_in[6];
    A.as2 = (const float*)d_in[7];
    A.ad2 = (const float*)d_in[8];
    A.b2  = (const float*)d_in[9];
    A.w3  = (const float*)d_in[10];
    A.as3 = (const float*)d_in[11];
    A.ad3 = (const float*)d_in[12];
    A.b3  = (const float*)d_in[13];
    A.wn  = (const float*)d_in[14];
    A.bn  = (const float*)d_in[15];
    A.wg  = (const float*)d_in[16];
    A.bg  = (const float*)d_in[17];
    A.wv  = (const float*)d_in[18];
    A.bv  = (const float*)d_in[19];
    A.outp = (float*)d_out;

    char* wsb = (char*)d_ws;
    A.amask = (uint64_t*)(wsb);                       // 1 MB
    A.hbT  = (ushort*)(wsb + (1u  << 20));            // 4 MB
    A.xbA  = (ushort*)(wsb + (5u  << 20));            // 4 MB
    A.xbB  = (ushort*)(wsb + (9u  << 20));            // 4 MB
    A.x0b  = (ushort*)(wsb + (13u << 20));            // 1 MB
    char* tail = wsb + (14u << 20);
    A.s_buf = (float*)(tail);                         // 128 KB
    A.d_buf = (float*)(tail + (1u << 17));            // 128 KB
    A.wb1  = (ushort*)(tail + (2u << 17));            // 32 KB
    A.wb2  = (ushort*)(tail + (2u << 17) + (1u << 15));  // 128 KB
    A.wb3  = (ushort*)(tail + (2u << 17) + (5u << 15));  // 32 KB
    A.wnb  = (ushort*)(tail + (2u << 17) + (6u << 15));  // 8 KB
    A.gsum = (float*) (tail + (2u << 17) + (6u << 15) + (1u << 13)); // 2 KB
    A.bar  = (unsigned*)(tail + (2u << 17) + (6u << 15) + (1u << 13) + 4096);

    // grid sized to guaranteed co-residency (occupancy query is host-side,
    // deterministic, capture-safe); MI355X has 256 CUs.
    int nb = 0;
    if (hipOccupancyMaxActiveBlocksPerMultiprocessor(&nb, gat_fused, 256, 0) != hipSuccess || nb < 1)
        nb = 1;
    int nblk = nb * 256;
    if (nblk > 2048) nblk = 2048;
    A.nblk = nblk;

    hipMemsetAsync(A.bar, 0, 256, stream);            // zero barrier counter
    gat_fused<<<nblk, 256, 0, stream>>>(A);
}

// Round 8
// 179.022 us; speedup vs baseline: 3.6964x; 3.6964x over previous
//
#include <hip/hip_runtime.h>
#include <stdint.h>

#define NB 8
#define NN 1024
#define LOG2E 1.44269504088896f

typedef short short8 __attribute__((ext_vector_type(8)));
typedef float floatx4 __attribute__((ext_vector_type(4)));

static __device__ __forceinline__ short f2bf(float x) {   // round-nearest-even
    union { float f; uint32_t u; } v; v.f = x;
    uint32_t r = (v.u + 0x7fffu + ((v.u >> 16) & 1u)) >> 16;
    return (short)r;
}

// ---------------- prep: adjacency bitmask + weight cvt + gsum zero ----------
__global__ __launch_bounds__(256) void prep_all(const int* __restrict__ adj,
        uint64_t* __restrict__ am,
        const float* __restrict__ w1, const float* __restrict__ w2,
        const float* __restrict__ w3, const float* __restrict__ wn,
        ushort* __restrict__ wb1, ushort* __restrict__ wb2,
        ushort* __restrict__ wb3, ushort* __restrict__ wnb,
        float* __restrict__ gsum) {
    if (blockIdx.x < 2048) {
        int wave = blockIdx.x * 4 + (threadIdx.x >> 6);
        int lane = threadIdx.x & 63;
        int b = wave >> 10;
        int i = wave & 1023;
        const int* row = adj + ((size_t)b * NN + i) * NN;
        uint64_t* outp = am + ((size_t)b * NN + i) * 16;
        for (int it = 0; it < 16; ++it) {
            int j = it * 64 + lane;
            int v = (row[j] > 0) || (j == i);
            uint64_t m = __ballot(v);
            if (lane == 0) outp[it] = m;
        }
        return;
    }
    int idx = (blockIdx.x - 2048) * 256 + threadIdx.x;
    const float* src; ushort* dst; int li;
    if (idx < 4096)        { src = w1; dst = wb1; li = idx; }
    else if (idx < 20480)  { src = w2; dst = wb2; li = idx - 4096; }
    else if (idx < 24576)  { src = w3; dst = wb3; li = idx - 20480; }
    else if (idx < 25600)  { src = wn; dst = wnb; li = idx - 24576; }
    else if (idx < 25728) {
        ((float4*)gsum)[idx - 25600] = make_float4(0.f, 0.f, 0.f, 0.f);
        return;
    } else return;
    float4 v = ((const float4*)src)[li];
    ushort4 o;
    o.x = (ushort)f2bf(v.x); o.y = (ushort)f2bf(v.y);
    o.z = (ushort)f2bf(v.z); o.w = (ushort)f2bf(v.w);
    ((ushort4*)dst)[li] = o;
}

// ---------------- MFMA GEMM: H = X @ W^T, fused s/d epilogue ----------------
// Output written in MFMA-B-FRAGMENT order: hbF[(b,hd)][jc][ks][ct][lane][u],
// so the aggregation loads fragments with single coalesced dwordx4's.
// CVT: X is fp32 (layer 1), converted during LDS staging.
template<int K, bool CVT>
__global__ __launch_bounds__(256, 4) void gemm_mfma(const void* __restrict__ Xv,
        const ushort* __restrict__ Wt, ushort* __restrict__ hbF,
        const float* __restrict__ asrc, const float* __restrict__ adst,
        float* __restrict__ s_t, float* __restrict__ d_t, int nheads) {
    __shared__ ushort smem[2][64][88];
    int m0 = blockIdx.x * 64, n0 = blockIdx.y * 64;
    int hd = blockIdx.y;
    int tid = threadIdx.x, w = tid >> 6, L = tid & 63;
    int m15 = L & 15, kq = L >> 4;
    floatx4 acc[4];
#pragma unroll
    for (int ct = 0; ct < 4; ++ct) acc[ct] = (floatx4){0.f, 0.f, 0.f, 0.f};

    for (int k0 = 0; k0 < K; k0 += 64) {
#pragma unroll
        for (int it = 0; it < 2; ++it) {
            int idx = tid + it * 256;
            int r = idx >> 3, sg = idx & 7;
            if (CVT) {
                const float* xf = (const float*)Xv + (size_t)(m0 + r) * K + k0 + sg * 8;
                float4 a0 = *(const float4*)xf, a1 = *(const float4*)(xf + 4);
                ushort t8[8];
                t8[0] = (ushort)f2bf(a0.x); t8[1] = (ushort)f2bf(a0.y);
                t8[2] = (ushort)f2bf(a0.z); t8[3] = (ushort)f2bf(a0.w);
                t8[4] = (ushort)f2bf(a1.x); t8[5] = (ushort)f2bf(a1.y);
                t8[6] = (ushort)f2bf(a1.z); t8[7] = (ushort)f2bf(a1.w);
                *(uint4*)&smem[0][r][sg * 8] = *(uint4*)&t8[0];
            } else {
                const ushort* xs = (const ushort*)Xv + (size_t)(m0 + r) * K + k0 + sg * 8;
                *(uint4*)&smem[0][r][sg * 8] = *(const uint4*)xs;
            }
            *(uint4*)&smem[1][r][sg * 8] = *(const uint4*)&Wt[(size_t)(n0 + r) * K + k0 + sg * 8];
        }
        __syncthreads();
#pragma unroll
        for (int ks = 0; ks < 2; ++ks) {
            short8 a = *(const short8*)&smem[0][16 * w + m15][ks * 32 + kq * 8];
#pragma unroll
            for (int ct = 0; ct < 4; ++ct) {
                short8 bfr = *(const short8*)&smem[1][ct * 16 + m15][ks * 32 + kq * 8];
                acc[ct] = __builtin_amdgcn_mfma_f32_16x16x32_bf16(a, bfr, acc[ct], 0, 0, 0);
            }
        }
        __syncthreads();
    }

    // ---- fused s/d epilogue ----
    float asv[4], adv[4];
#pragma unroll
    for (int ct = 0; ct < 4; ++ct) {
        asv[ct] = asrc[hd * 64 + ct * 16 + m15];
        adv[ct] = adst[hd * 64 + ct * 16 + m15];
    }
#pragma unroll
    for (int r = 0; r < 4; ++r) {
        float sp = acc[0][r] * asv[0] + acc[1][r] * asv[1] + acc[2][r] * asv[2] + acc[3][r] * asv[3];
        float dp = acc[0][r] * adv[0] + acc[1][r] * adv[1] + acc[2][r] * adv[2] + acc[3][r] * adv[3];
#pragma unroll
        for (int off = 1; off < 16; off <<= 1) {
            sp += __shfl_xor(sp, off);
            dp += __shfl_xor(dp, off);
        }
        if (m15 == 0) {
            int mg = m0 + 16 * w + kq * 4 + r;
            int bb = mg >> 10, node = mg & 1023;
            s_t[((size_t)(bb * nheads + hd)) * NN + node] = sp;
            d_t[((size_t)(bb * nheads + hd)) * NN + node] = dp;
        }
    }

    // ---- rearrange to B-fragment order via LDS, then coalesced 8KB store ----
    // frag element (lane Lf, u) of (ks,ct) = H[c=ct*16+(Lf&15)][j=jc*64+ks*32+(Lf>>4)*8+u]
    ushort* tb = (ushort*)smem;    // 4096 ushorts, laid out (ks*4+ct)*512 + Lf*8 + u
    int jj0 = 16 * w + kq * 4;     // this lane's 4 outputs: u contiguous
    int ks0 = jj0 >> 5, l4 = (jj0 >> 3) & 3, u0 = jj0 & 7;
#pragma unroll
    for (int ct = 0; ct < 4; ++ct) {
        ushort p4[4];
#pragma unroll
        for (int r = 0; r < 4; ++r) p4[r] = (ushort)f2bf(acc[ct][r]);
        *(ushort4*)&tb[(ks0 * 4 + ct) * 512 + (l4 * 16 + m15) * 8 + u0] = *(ushort4*)&p4[0];
    }
    __syncthreads();
    int bb = m0 >> 10, node0 = m0 & 1023, jc = node0 >> 6;
    size_t dstb = ((size_t)(bb * nheads + hd) * 16 + jc) * 4096;
#pragma unroll
    for (int e = 0; e < 2; ++e) {
        int idx = tid + e * 256;
        *(uint4*)&hbF[dstb + (size_t)idx * 8] = *(const uint4*)&tb[idx * 8];
    }
}

// ---------------- MFMA masked-softmax aggregation: register B-frags ----------
// grid (64, nheads, 8): 16-row i-tiles, wave w owns j-quarter [w*256,(w+1)*256).
// B-fragments load straight from hbF with one coalesced dwordx4 per frag,
// double-buffered in registers. No LDS staging at all; zero j-loop barriers.
__global__ __launch_bounds__(256, 4) void gat_agg_mfma(
        const ushort* __restrict__ hbF, const uint64_t* __restrict__ am,
        const float* __restrict__ s_t, const float* __restrict__ d_t,
        const float* __restrict__ bias, ushort* __restrict__ Xb,
        float* __restrict__ gsum, int nheads, int do_colsum) {
    __shared__ __align__(16) float s_lds[NN];     // 4 KB
    __shared__ float red4[4];
    __shared__ __align__(16) float fb[4][17][68]; // partials + denom row, 18.5 KB

    int i0 = blockIdx.x * 16;
    int hd = blockIdx.y;
    int b  = blockIdx.z;
    int HC = nheads * 64;
    int tid = threadIdx.x, w = tid >> 6, L = tid & 63;
    int m15 = L & 15, kq = L >> 4;

    // stage s + global max
    const float* srow = s_t + ((size_t)b * nheads + hd) * NN;
    float4 s4 = ((const float4*)srow)[tid];
    *(float4*)&s_lds[tid * 4] = s4;
    float lm = fmaxf(fmaxf(s4.x, s4.y), fmaxf(s4.z, s4.w));
#pragma unroll
    for (int off = 32; off; off >>= 1) lm = fmaxf(lm, __shfl_xor(lm, off));
    if (L == 0) red4[w] = lm;

    // per-lane adjacency words (row i0+m15, chunks w*4..w*4+3) + d_i
    const uint64_t* amrow = am + ((size_t)b * NN + i0 + m15) * 16 + w * 4;
    uint64_t aw[4];
    *(uint4*)&aw[0] = *(const uint4*)&amrow[0];
    *(uint4*)&aw[2] = *(const uint4*)&amrow[2];
    float d_i = d_t[((size_t)b * nheads + hd) * NN + i0 + m15];
    __syncthreads();

    float smax = fmaxf(fmaxf(red4[0], red4[1]), fmaxf(red4[2], red4[3]));
    float t0 = smax + d_i;
    float m_up = fmaxf(t0, 0.2f * t0);   // exp-safe upper bound (leaky monotone)
    float m2n = -m_up * LOG2E;

    floatx4 acc[4];
#pragma unroll
    for (int ct = 0; ct < 4; ++ct) acc[ct] = (floatx4){0.f, 0.f, 0.f, 0.f};
    float lsum = 0.f;

    const ushort* hs = hbF + (size_t)(b * nheads + hd) * 16 * 4096;
    int wq = w * 4;

    uint4 fr[2][4];
#define LOADG(dst, g) { int t_ = (g) >> 1, ks_ = (g) & 1;                          \
    const ushort* bp = hs + ((size_t)((wq + t_) * 8 + ks_ * 4)) * 512 + (size_t)L * 8; \
    dst[0] = *(const uint4*)bp;            dst[1] = *(const uint4*)(bp + 512);     \
    dst[2] = *(const uint4*)(bp + 1024);   dst[3] = *(const uint4*)(bp + 1536); }

    LOADG(fr[0], 0);
#pragma unroll
    for (int g = 0; g < 8; ++g) {
        if (g < 7) LOADG(fr[(g + 1) & 1], g + 1);
        int t = g >> 1, ks = g & 1;
        int jb = (wq + t) * 64 + ks * 32 + kq * 8;
        float sv[8];
        *(float4*)&sv[0] = *(const float4*)&s_lds[jb];
        *(float4*)&sv[4] = *(const float4*)&s_lds[jb + 4];
        unsigned byte = (unsigned)((aw[t] >> (ks * 32 + kq * 8)) & 0xffull);
        unsigned ue[8];
#pragma unroll
        for (int u = 0; u < 8; ++u) {
            float sc = sv[u] + d_i;
            float lk = fmaxf(sc, 0.2f * sc);
#if __has_builtin(__builtin_amdgcn_exp2f)
            float arg = __builtin_fmaf(lk, LOG2E, m2n);
            arg = ((byte >> u) & 1u) ? arg : -1e30f;
            float e = __builtin_amdgcn_exp2f(arg);
#else
            float e = __expf(fminf(lk + m2n, 0.f));
            e = ((byte >> u) & 1u) ? e : 0.f;
#endif
            lsum += e;
            ue[u] = __float_as_uint(e);
        }
        unsigned pk[4];
#pragma unroll
        for (int k2 = 0; k2 < 4; ++k2)
#if __has_builtin(__builtin_amdgcn_perm)
            pk[k2] = __builtin_amdgcn_perm(ue[2 * k2 + 1], ue[2 * k2], 0x07060302u);
#else
            pk[k2] = (ue[2 * k2] >> 16) | (ue[2 * k2 + 1] & 0xffff0000u);
#endif
        short8 afrag;
        *(uint4*)&afrag = *(uint4*)&pk[0];
#pragma unroll
        for (int ct = 0; ct < 4; ++ct) {
            short8 bfr;
            *(uint4*)&bfr = fr[g & 1][ct];
            acc[ct] = __builtin_amdgcn_mfma_f32_16x16x32_bf16(afrag, bfr, acc[ct], 0, 0, 0);
        }
    }
#undef LOADG

    // partial denom for row m15 over this wave's j-quarter
    lsum += __shfl_xor(lsum, 16);
    lsum += __shfl_xor(lsum, 32);

    // publish partials
#pragma unroll
    for (int ct = 0; ct < 4; ++ct)
#pragma unroll
        for (int r = 0; r < 4; ++r)
            fb[w][kq * 4 + r][ct * 16 + m15] = acc[ct][r];
    if (kq == 0) fb[w][16][m15] = lsum;
    __syncthreads();

    // combine 4 waves' partials; epilogue relu(acc/l + bias) -> bf16
    int rr = tid >> 4, c0 = (tid & 15) * 4;
    float s0 = 0.f, s1 = 0.f, s2 = 0.f, s3 = 0.f, ltot = 0.f;
#pragma unroll
    for (int w2 = 0; w2 < 4; ++w2) {
        float4 a4 = *(const float4*)&fb[w2][rr][c0];
        s0 += a4.x; s1 += a4.y; s2 += a4.z; s3 += a4.w;
        ltot += fb[w2][16][rr];
    }
    float li = 1.f / ltot;
    float4 bv = *(const float4*)&bias[hd * 64 + c0];
    float v0 = fmaxf(s0 * li + bv.x, 0.f);
    float v1 = fmaxf(s1 * li + bv.y, 0.f);
    float v2 = fmaxf(s2 * li + bv.z, 0.f);
    float v3 = fmaxf(s3 * li + bv.w, 0.f);
    ushort4 o;
    o.x = (ushort)f2bf(v0); o.y = (ushort)f2bf(v1);
    o.z = (ushort)f2bf(v2); o.w = (ushort)f2bf(v3);
    *(ushort4*)&Xb[((size_t)(b * NN + i0 + rr)) * HC + hd * 64 + c0] = o;

    if (do_colsum) {
        __syncthreads();
        *(float4*)&fb[0][rr][c0] = make_float4(v0, v1, v2, v3);
        __syncthreads();
        if (tid < 64) {
            float s = 0.f;
#pragma unroll
            for (int r2 = 0; r2 < 16; ++r2) s += fb[0][r2][tid];
            atomicAdd(&gsum[b * 64 + tid], s);
        }
    }
}

// ---------------- fused readout: gc + relu(X@wn.T+bn)·wv + gc ----------------
__global__ __launch_bounds__(256) void readout_fused(
        const ushort* __restrict__ xb, const ushort* __restrict__ wnb,
        const float* __restrict__ bn, const float* __restrict__ wg,
        const float* __restrict__ bg, const float* __restrict__ wv,
        const float* __restrict__ bv, const float* __restrict__ gsum,
        float* __restrict__ outp) {
    __shared__ ushort xs[64][88];
    __shared__ ushort wns[64][88];
    __shared__ float gcs;
    int b = blockIdx.y, n0 = blockIdx.x * 64;
    int tid = threadIdx.x, w = tid >> 6, L = tid & 63;
    int m15 = L & 15, kq = L >> 4;
#pragma unroll
    for (int it = 0; it < 2; ++it) {
        int idx = tid + it * 256;
        int r = idx >> 3, sg = idx & 7;
        *(uint4*)&xs[r][sg * 8]  = *(const uint4*)&xb[(size_t)(b * NN + n0 + r) * 64 + sg * 8];
        *(uint4*)&wns[r][sg * 8] = *(const uint4*)&wnb[r * 64 + sg * 8];
    }
    if (tid < 64) {
        float acc = bg[tid];
#pragma unroll 8
        for (int c = 0; c < 64; ++c) acc += gsum[b * 64 + c] * wg[tid * 64 + c];
        acc = fmaxf(acc, 0.f) * wv[64 + tid];
#pragma unroll
        for (int off = 32; off; off >>= 1) acc += __shfl_down(acc, off);
        if (tid == 0) gcs = acc + bv[0];
    }
    __syncthreads();

    floatx4 acc[4];
#pragma unroll
    for (int ct = 0; ct < 4; ++ct) acc[ct] = (floatx4){0.f, 0.f, 0.f, 0.f};
#pragma unroll
    for (int ks = 0; ks < 2; ++ks) {
        short8 a = *(const short8*)&xs[16 * w + m15][ks * 32 + kq * 8];
#pragma unroll
        for (int ct = 0; ct < 4; ++ct) {
            short8 bfr = *(const short8*)&wns[ct * 16 + m15][ks * 32 + kq * 8];
            acc[ct] = __builtin_amdgcn_mfma_f32_16x16x32_bf16(a, bfr, acc[ct], 0, 0, 0);
        }
    }
    float bnv[4], wvv[4];
#pragma unroll
    for (int ct = 0; ct < 4; ++ct) {
        bnv[ct] = bn[ct * 16 + m15];
        wvv[ct] = wv[ct * 16 + m15];
    }
    float gc = gcs;
#pragma unroll
    for (int r = 0; r < 4; ++r) {
        float rp = 0.f;
#pragma unroll
        for (int ct = 0; ct < 4; ++ct)
            rp += fmaxf(acc[ct][r] + bnv[ct], 0.f) * wvv[ct];
#pragma unroll
        for (int off = 1; off < 16; off <<= 1) rp += __shfl_xor(rp, off);
        if (m15 == 0)
            outp[(size_t)b * NN + n0 + 16 * w + kq * 4 + r] = rp + gc;
    }
}

extern "C" void kernel_launch(void* const* d_in, const int* in_sizes, int n_in,
                              void* d_out, int out_size, void* d_ws, size_t ws_size,
                              hipStream_t stream) {
    const float* x0  = (const float*)d_in[0];
    const int*   adj = (const int*)  d_in[1];
    const float* w1  = (const float*)d_in[2];
    const float* as1 = (const float*)d_in[3];
    const float* ad1 = (const float*)d_in[4];
    const float* b1  = (const float*)d_in[5];
    const float* w2  = (const float*)d_in[6];
    const float* as2 = (const float*)d_in[7];
    const float* ad2 = (const float*)d_in[8];
    const float* b2  = (const float*)d_in[9];
    const float* w3  = (const float*)d_in[10];
    const float* as3 = (const float*)d_in[11];
    const float* ad3 = (const float*)d_in[12];
    const float* b3  = (const float*)d_in[13];
    const float* wn  = (const float*)d_in[14];
    const float* bn  = (const float*)d_in[15];
    const float* wg  = (const float*)d_in[16];
    const float* bg  = (const float*)d_in[17];
    const float* wv  = (const float*)d_in[18];
    const float* bv  = (const float*)d_in[19];
    float* outp = (float*)d_out;

    char* wsb = (char*)d_ws;
    uint64_t* amask = (uint64_t*)(wsb);                      // 1 MB
    ushort* hbF  = (ushort*)(wsb + (1u  << 20));             // 4 MB (frag order)
    ushort* xbA  = (ushort*)(wsb + (5u  << 20));             // 4 MB
    ushort* xbB  = (ushort*)(wsb + (9u  << 20));             // 4 MB
    char* tail   = wsb + (14u << 20);
    float* s_buf = (float*)(tail);                           // 128 KB
    float* d_buf = (float*)(tail + (1u << 17));              // 128 KB
    ushort* wb1  = (ushort*)(tail + (2u << 17));             // 32 KB
    ushort* wb2  = (ushort*)(tail + (2u << 17) + (1u << 15));// 128 KB
    ushort* wb3  = (ushort*)(tail + (2u << 17) + (5u << 15));// 32 KB
    ushort* wnb  = (ushort*)(tail + (2u << 17) + (6u << 15));// 8 KB
    float* gsum  = (float*) (tail + (2u << 17) + (6u << 15) + (1u << 13));

    prep_all<<<2149, 256, 0, stream>>>(adj, amask, w1, w2, w3, wn,
                                       wb1, wb2, wb3, wnb, gsum);

    // layer 1 (K=64, H=4; x0 converted in-staging)
    gemm_mfma<64, true><<<dim3(128, 4), 256, 0, stream>>>(x0, wb1, hbF, as1, ad1, s_buf, d_buf, 4);
    gat_agg_mfma<<<dim3(64, 4, 8), 256, 0, stream>>>(hbF, amask, s_buf, d_buf, b1, xbA, gsum, 4, 0);

    // layer 2 (K=256, H=4)
    gemm_mfma<256, false><<<dim3(128, 4), 256, 0, stream>>>(xbA, wb2, hbF, as2, ad2, s_buf, d_buf, 4);
    gat_agg_mfma<<<dim3(64, 4, 8), 256, 0, stream>>>(hbF, amask, s_buf, d_buf, b2, xbB, gsum, 4, 0);

    // layer 3 (K=256, H=1) + fused column-sum
    gemm_mfma<256, false><<<dim3(128, 1), 256, 0, stream>>>(xbB, wb3, hbF, as3, ad3, s_buf, d_buf, 1);
    gat_agg_mfma<<<dim3(64, 1, 8), 256, 0, stream>>>(hbF, amask, s_buf, d_buf, b3, xbA, gsum, 1, 1);

    // fused readout
    readout_fused<<<dim3(16, 8), 256, 0, stream>>>(xbA, wnb, bn, wg, bg, wv, bv, gsum, outp);
}